// Round 1
// baseline (1620.800 us; speedup 1.0000x reference)
//
#include <hip/hip_runtime.h>
#include <math.h>

// ---------------------------------------------------------------------------
// GCN forward: h = x@Wp+bp; 4x { msc=(h@W)*dinv ; h += relu(dinv*(gather-sum)+B) };
// heads: p1=relu(h@Wp1+b); p2=relu(p1@Wp2+b); r=relu(h@Wr1+b);
// pos=p2@Wp3+b; rad=sigmoid(r@Wr2+b); out=pos/(|pos|+1e-8)*rad
// Round 1: all fp32, CSR-based aggregation (no feature atomics).
// ---------------------------------------------------------------------------

__global__ void count_kernel(const int* __restrict__ dst, int E, int* __restrict__ cnt) {
    int i = blockIdx.x * blockDim.x + threadIdx.x;
    if (i < E) atomicAdd(&cnt[dst[i]], 1);
}

__global__ void dinv_kernel(const int* __restrict__ cnt, int M, float* __restrict__ dinv) {
    int i = blockIdx.x * blockDim.x + threadIdx.x;
    if (i < M) dinv[i] = rsqrtf((float)cnt[i] + 1.0f);  // deg = in-deg + self-loop >= 1
}

__global__ void scan1_kernel(const int* __restrict__ cnt, int M,
                             int* __restrict__ rowptr, int* __restrict__ bsum) {
    __shared__ int s[256];
    int t = threadIdx.x;
    int i = blockIdx.x * 256 + t;
    int v = (i < M) ? cnt[i] : 0;
    s[t] = v; __syncthreads();
    for (int o = 1; o < 256; o <<= 1) {
        int x = (t >= o) ? s[t - o] : 0;
        __syncthreads();
        s[t] += x;
        __syncthreads();
    }
    if (i < M) rowptr[i] = s[t] - v;          // exclusive
    if (t == 255) bsum[blockIdx.x] = s[255];  // block total
}

__global__ void scan2_kernel(const int* __restrict__ bsum, int nb, int* __restrict__ boff) {
    __shared__ int s[256];
    int t = threadIdx.x;
    int v = (t < nb) ? bsum[t] : 0;
    s[t] = v; __syncthreads();
    for (int o = 1; o < 256; o <<= 1) {
        int x = (t >= o) ? s[t - o] : 0;
        __syncthreads();
        s[t] += x;
        __syncthreads();
    }
    if (t < nb) boff[t] = s[t] - v;  // exclusive
}

__global__ void scan3_kernel(int* __restrict__ rowptr, int M, int E, const int* __restrict__ boff) {
    int i = blockIdx.x * 256 + threadIdx.x;
    if (i < M) rowptr[i] += boff[blockIdx.x];
    if (i == M) rowptr[M] = E;
}

__global__ void fill_kernel(const int* __restrict__ src, const int* __restrict__ dst, int E,
                            const int* __restrict__ rowptr, int* __restrict__ cursor,
                            int* __restrict__ csr) {
    int i = blockIdx.x * blockDim.x + threadIdx.x;
    if (i < E) {
        int d = dst[i];
        int slot = atomicAdd(&cursor[d], 1);
        csr[rowptr[d] + slot] = src[i];
    }
}

// ---------------------------------------------------------------------------
// Tall-skinny fp32 GEMM: C[M x NN] = act(A[M x K] @ W[K x NN] + bias) * rowscale
// 192 threads/block, 64-row tile. GDIV=1 -> NN=192 (1 col/thread, 64 rows),
// GDIV=2 -> NN=96 (1 col/thread, 2 row-groups of 32 rows).
// A-tile staged in LDS [64][16]; reads are block-uniform broadcast b128.
// w[16] in registers, reused across all rows of the tile.
// ---------------------------------------------------------------------------
template <int ACT, int GDIV>
__global__ __launch_bounds__(192) void gemm_kernel(
    const float* __restrict__ A, const float* __restrict__ W,
    const float* __restrict__ bias, const float* __restrict__ rowscale,
    float* __restrict__ C, int M, int K) {
    constexpr int NN = 192 / GDIV;
    constexpr int TM = 64;
    constexpr int KC = 16;
    constexpr int R = TM / GDIV;

    __shared__ float As[TM][KC];
    const int tid = threadIdx.x;
    const int f = tid % NN;
    const int g = tid / NN;
    const long row0 = (long)blockIdx.x * TM;

    float acc[R];
#pragma unroll
    for (int i = 0; i < R; i++) acc[i] = 0.f;

    for (int k0 = 0; k0 < K; k0 += KC) {
        __syncthreads();
        // stage A tile: 64 rows x 16 k, as float4 along k (coalesced)
#pragma unroll
        for (int it = 0; it < 2; ++it) {
            int i = tid + it * 192;
            if (i < TM * KC / 4) {
                int r = i >> 2, kq = i & 3;
                float4 v = make_float4(0.f, 0.f, 0.f, 0.f);
                if (row0 + r < M)
                    v = *reinterpret_cast<const float4*>(&A[(size_t)(row0 + r) * K + k0 + kq * 4]);
                *reinterpret_cast<float4*>(&As[r][kq * 4]) = v;
            }
        }
        __syncthreads();
        float w[KC];
#pragma unroll
        for (int kk = 0; kk < KC; kk++) w[kk] = W[(size_t)(k0 + kk) * NN + f];
#pragma unroll
        for (int rr = 0; rr < R; rr++) {
            const float4* ap = reinterpret_cast<const float4*>(&As[g * R + rr][0]);
#pragma unroll
            for (int kq = 0; kq < KC / 4; kq++) {
                float4 a = ap[kq];
                acc[rr] = fmaf(a.x, w[4 * kq + 0], acc[rr]);
                acc[rr] = fmaf(a.y, w[4 * kq + 1], acc[rr]);
                acc[rr] = fmaf(a.z, w[4 * kq + 2], acc[rr]);
                acc[rr] = fmaf(a.w, w[4 * kq + 3], acc[rr]);
            }
        }
    }
    float bv = bias ? bias[f] : 0.f;
#pragma unroll
    for (int rr = 0; rr < R; rr++) {
        long row = row0 + g * R + rr;
        if (row < M) {
            float v = acc[rr] + bv;
            if (ACT == 1) v = fmaxf(v, 0.f);
            if (rowscale) v *= rowscale[row];
            C[(size_t)row * NN + f] = v;
        }
    }
}

// ---------------------------------------------------------------------------
// Per-node gather aggregation: h[n] += relu(dinv[n]*(msc[n] + sum_e msc[src_e]) + B)
// msc already carries the per-source dinv scaling (GEMM epilogue rowscale).
// One block (192 threads = one feature each) per node; edge indices staged in LDS.
// ---------------------------------------------------------------------------
__global__ __launch_bounds__(192) void aggregate_kernel(
    const float* __restrict__ msc, const int* __restrict__ csr,
    const int* __restrict__ rowptr, const float* __restrict__ dinv,
    const float* __restrict__ bias, float* __restrict__ h) {
    const int n = blockIdx.x;
    const int f = threadIdx.x;
    const int beg = rowptr[n], end = rowptr[n + 1];
    __shared__ int sidx[256];
    float acc = msc[(size_t)n * 192 + f];  // self-loop term (already * dinv[n])
    for (int e0 = beg; e0 < end; e0 += 256) {
        const int cnt = min(256, end - e0);
        __syncthreads();
        for (int i = f; i < cnt; i += 192) sidx[i] = csr[e0 + i];
        __syncthreads();
        for (int i = 0; i < cnt; i++)
            acc += msc[(size_t)sidx[i] * 192 + f];
    }
    float v = acc * dinv[n] + bias[f];
    h[(size_t)n * 192 + f] += fmaxf(v, 0.f);
}

// ---------------------------------------------------------------------------
// Tail: pos = p2 @ Wp3 + bp3 (96->2); rad = sigmoid(r @ Wr2 + br2) (96->1);
// out = pos / (|pos| + 1e-8) * rad. One thread per node, float4 row reads.
// ---------------------------------------------------------------------------
__global__ void finalize_kernel(const float* __restrict__ p2, const float* __restrict__ rbuf,
                                const float* __restrict__ Wp3, const float* __restrict__ bp3,
                                const float* __restrict__ Wr2, const float* __restrict__ br2,
                                float* __restrict__ out, int M) {
    int n = blockIdx.x * blockDim.x + threadIdx.x;
    if (n >= M) return;
    const float4* p = reinterpret_cast<const float4*>(p2 + (size_t)n * 96);
    const float4* r = reinterpret_cast<const float4*>(rbuf + (size_t)n * 96);
    float a0 = 0.f, a1 = 0.f, rr = 0.f;
#pragma unroll
    for (int q = 0; q < 24; q++) {
        float4 pv = p[q];
        float4 rv = r[q];
        float4 w01 = reinterpret_cast<const float4*>(Wp3)[2 * q];      // rows 4q,4q+1
        float4 w23 = reinterpret_cast<const float4*>(Wp3)[2 * q + 1];  // rows 4q+2,4q+3
        a0 += pv.x * w01.x + pv.y * w01.z + pv.z * w23.x + pv.w * w23.z;
        a1 += pv.x * w01.y + pv.y * w01.w + pv.z * w23.y + pv.w * w23.w;
        float4 wr = reinterpret_cast<const float4*>(Wr2)[q];
        rr += rv.x * wr.x + rv.y * wr.y + rv.z * wr.z + rv.w * wr.w;
    }
    a0 += bp3[0];
    a1 += bp3[1];
    rr += br2[0];
    float radius = 1.f / (1.f + expf(-rr));
    float nrm = sqrtf(a0 * a0 + a1 * a1) + 1e-8f;
    float s = radius / nrm;
    out[(size_t)n * 2 + 0] = a0 * s;
    out[(size_t)n * 2 + 1] = a1 * s;
}

extern "C" void kernel_launch(void* const* d_in, const int* in_sizes, int n_in,
                              void* d_out, int out_size, void* d_ws, size_t ws_size,
                              hipStream_t stream) {
    const float* x     = (const float*)d_in[0];
    const int*   ei    = (const int*)d_in[1];
    const float* Wp    = (const float*)d_in[2];
    const float* bp    = (const float*)d_in[3];
    const float* convW = (const float*)d_in[4];
    const float* convB = (const float*)d_in[5];
    const float* Wp1   = (const float*)d_in[6];
    const float* bp1   = (const float*)d_in[7];
    const float* Wp2   = (const float*)d_in[8];
    const float* bp2   = (const float*)d_in[9];
    const float* Wp3   = (const float*)d_in[10];
    const float* bp3   = (const float*)d_in[11];
    const float* Wr1   = (const float*)d_in[12];
    const float* br1   = (const float*)d_in[13];
    const float* Wr2   = (const float*)d_in[14];
    const float* br2   = (const float*)d_in[15];
    float* out = (float*)d_out;

    const int M = in_sizes[0] / 128;  // 50000 nodes
    const int E = in_sizes[1] / 2;    // 800000 edges
    const int* srcI = ei;
    const int* dstI = ei + E;

    char* w = (char*)d_ws;
    size_t off = 0;
    auto alloc = [&](size_t b) { size_t o = off; off += (b + 255) & ~(size_t)255; return o; };
    float* h      = (float*)(w + alloc((size_t)M * 192 * 4));
    float* msc    = (float*)(w + alloc((size_t)M * 192 * 4));  // also reused for p1
    float* p2     = (float*)(w + alloc((size_t)M * 96 * 4));
    float* rb     = (float*)(w + alloc((size_t)M * 96 * 4));
    int*   cnt    = (int*)(w + alloc((size_t)M * 4));
    float* dinv   = (float*)(w + alloc((size_t)M * 4));
    int*   rowptr = (int*)(w + alloc((size_t)(M + 1) * 4));
    int*   cursor = (int*)(w + alloc((size_t)M * 4));
    int*   csr    = (int*)(w + alloc((size_t)E * 4));
    int*   bsum   = (int*)(w + alloc(256 * 4));
    int*   boff   = (int*)(w + alloc(256 * 4));

    hipMemsetAsync(cnt, 0, (size_t)M * 4, stream);
    hipMemsetAsync(cursor, 0, (size_t)M * 4, stream);

    count_kernel<<<(E + 255) / 256, 256, 0, stream>>>(dstI, E, cnt);
    dinv_kernel<<<(M + 255) / 256, 256, 0, stream>>>(cnt, M, dinv);

    int nb = (M + 255) / 256;  // 196 scan blocks
    scan1_kernel<<<nb, 256, 0, stream>>>(cnt, M, rowptr, bsum);
    scan2_kernel<<<1, 256, 0, stream>>>(bsum, nb, boff);
    scan3_kernel<<<(M + 256) / 256, 256, 0, stream>>>(rowptr, M, E, boff);
    fill_kernel<<<(E + 255) / 256, 256, 0, stream>>>(srcI, dstI, E, rowptr, cursor, csr);

    int gb = (M + 63) / 64;  // 782 GEMM blocks
    // h = x @ Wp + bp
    gemm_kernel<0, 1><<<gb, 192, 0, stream>>>(x, Wp, bp, nullptr, h, M, 128);
    // 4 GCN layers
    for (int i = 0; i < 4; i++) {
        gemm_kernel<0, 1><<<gb, 192, 0, stream>>>(h, convW + (size_t)i * 192 * 192,
                                                  nullptr, dinv, msc, M, 192);
        aggregate_kernel<<<M, 192, 0, stream>>>(msc, csr, rowptr, dinv,
                                                convB + (size_t)i * 192, h);
    }
    // heads
    gemm_kernel<1, 1><<<gb, 192, 0, stream>>>(h, Wp1, bp1, nullptr, msc, M, 192);   // p1
    gemm_kernel<1, 2><<<gb, 192, 0, stream>>>(msc, Wp2, bp2, nullptr, p2, M, 192);  // p2
    gemm_kernel<1, 2><<<gb, 192, 0, stream>>>(h, Wr1, br1, nullptr, rb, M, 192);    // r
    finalize_kernel<<<(M + 255) / 256, 256, 0, stream>>>(p2, rb, Wp3, bp3, Wr2, br2, out, M);
}

// Round 3
// 850.292 us; speedup vs baseline: 1.9062x; 1.9062x over previous
//
#include <hip/hip_runtime.h>
#include <math.h>

typedef __attribute__((ext_vector_type(8))) _Float16 f16x8;
typedef __attribute__((ext_vector_type(4))) _Float16 f16x4;
typedef __attribute__((ext_vector_type(4))) float f32x4;

// ---------------------------------------------------------------------------
// Precision scheme: every GEMM operand a is split into fp16 planes
//   a = ah + al/2048, al stored as (a-ah)*2048 (keeps residuals in fp16
//   normal range; unscaled residuals ~3e-5 would be subnormal).
// C = ah@wh + (ah@wl_s + al_s@wh)/2048  -> rel error ~2^-22 (fp32-grade).
// Needed because out = pos/(|pos|+1e-8) amplifies pos error ~650x.
// ---------------------------------------------------------------------------

// ------------------------- graph setup -------------------------------------
__global__ void count_kernel(const int* __restrict__ dst, int E, int* __restrict__ cnt) {
    int i = blockIdx.x * blockDim.x + threadIdx.x;
    if (i < E) atomicAdd(&cnt[dst[i]], 1);
}

__global__ void dinv_kernel(const int* __restrict__ cnt, int M, float* __restrict__ dinv) {
    int i = blockIdx.x * blockDim.x + threadIdx.x;
    if (i < M) dinv[i] = rsqrtf((float)cnt[i] + 1.0f);  // + self-loop
}

__global__ void scan1_kernel(const int* __restrict__ cnt, int M,
                             int* __restrict__ rowptr, int* __restrict__ bsum) {
    __shared__ int s[256];
    int t = threadIdx.x;
    int i = blockIdx.x * 256 + t;
    int v = (i < M) ? cnt[i] : 0;
    s[t] = v; __syncthreads();
    for (int o = 1; o < 256; o <<= 1) {
        int x = (t >= o) ? s[t - o] : 0;
        __syncthreads();
        s[t] += x;
        __syncthreads();
    }
    if (i < M) rowptr[i] = s[t] - v;
    if (t == 255) bsum[blockIdx.x] = s[255];
}

__global__ void scan2_kernel(const int* __restrict__ bsum, int nb, int* __restrict__ boff) {
    __shared__ int s[256];
    int t = threadIdx.x;
    int v = (t < nb) ? bsum[t] : 0;
    s[t] = v; __syncthreads();
    for (int o = 1; o < 256; o <<= 1) {
        int x = (t >= o) ? s[t - o] : 0;
        __syncthreads();
        s[t] += x;
        __syncthreads();
    }
    if (t < nb) boff[t] = s[t] - v;
}

__global__ void scan3_kernel(int* __restrict__ rowptr, int M, int E, const int* __restrict__ boff) {
    int i = blockIdx.x * 256 + threadIdx.x;
    if (i < M) rowptr[i] += boff[blockIdx.x];
    if (i == M) rowptr[M] = E;
}

__global__ void fill_kernel(const int* __restrict__ src, const int* __restrict__ dst, int E,
                            const int* __restrict__ rowptr, int* __restrict__ cursor,
                            int* __restrict__ csr) {
    int i = blockIdx.x * blockDim.x + threadIdx.x;
    if (i < E) {
        int d = dst[i];
        int slot = atomicAdd(&cursor[d], 1);
        csr[rowptr[d] + slot] = src[i];
    }
}

// ------------------------- converters --------------------------------------
__global__ void convert_x_kernel(const float* __restrict__ x, _Float16* __restrict__ xh,
                                 _Float16* __restrict__ xl, int n4) {
    int i = blockIdx.x * 256 + threadIdx.x;
    if (i < n4) {
        float4 v = reinterpret_cast<const float4*>(x)[i];
        f16x4 h = {(_Float16)v.x, (_Float16)v.y, (_Float16)v.z, (_Float16)v.w};
        reinterpret_cast<f16x4*>(xh)[i] = h;
        f16x4 l = {(_Float16)((v.x - (float)h[0]) * 2048.f),
                   (_Float16)((v.y - (float)h[1]) * 2048.f),
                   (_Float16)((v.z - (float)h[2]) * 2048.f),
                   (_Float16)((v.w - (float)h[3]) * 2048.f)};
        reinterpret_cast<f16x4*>(xl)[i] = l;
    }
}

struct WSeg { const float* src; _Float16* dh; _Float16* dl; int K; int N; };
struct WSegs { WSeg s[8]; };

// dh/dl are transposed planes: WT[n][k] = W[k][n]
__global__ void convert_wt_kernel(WSegs segs) {
    WSeg sg = segs.s[blockIdx.y];
    int i = blockIdx.x * 256 + threadIdx.x;
    if (i < sg.K * sg.N) {
        int n = i / sg.K, k = i - n * sg.K;
        float w = sg.src[(size_t)k * sg.N + n];
        _Float16 hi = (_Float16)w;
        sg.dh[i] = hi;
        sg.dl[i] = (_Float16)((w - (float)hi) * 2048.f);
    }
}

// ---------------------------------------------------------------------------
// Split-fp16 MFMA GEMM. 256 threads = 4 waves.
//   NN=192: ROWS=64,  wave w -> all rows, cols [w*48, w*48+48)
//   NN=96 : ROWS=128, wave w -> rows [(w>>1)*64..), cols [(w&1)*48..)
// K staged in 32-slabs, both planes, LDS stride 40 fp16 (2-way bank
// aliasing only = free). Per wave/slab: 4mt x 3nt x 3 MFMA (16x16x32 f16).
// OM bit0: fp32 out Cf; bit1: fp16 plane out (Ch, Cl scaled x2048).
// ---------------------------------------------------------------------------
template <int KK, int NN, int ACT, int OM>
__global__ __launch_bounds__(256) void mfma_gemm(
    const _Float16* __restrict__ Ah, const _Float16* __restrict__ Al,
    const _Float16* __restrict__ WhT, const _Float16* __restrict__ WlT,
    const float* __restrict__ bias, const float* __restrict__ rowscale,
    float* __restrict__ Cf, _Float16* __restrict__ Ch, _Float16* __restrict__ Cl,
    int M) {
    constexpr int ROWS = (NN == 192) ? 64 : 128;
    constexpr int STR = 40;  // 32 k + 8 pad
    __shared__ _Float16 As[2 * ROWS * STR];
    __shared__ _Float16 Bs[2 * NN * STR];

    const int tid = threadIdx.x;
    const int wave = tid >> 6, lane = tid & 63;
    const int quad = lane >> 4, l16 = lane & 15;
    const int m0 = (NN == 192) ? 0 : (wave >> 1) * 64;
    const int n0w = (NN == 192) ? wave * 48 : (wave & 1) * 48;
    const int row0 = blockIdx.x * ROWS;

    f32x4 acc[4][3], acc2[4][3];
#pragma unroll
    for (int mt = 0; mt < 4; ++mt)
#pragma unroll
        for (int nt = 0; nt < 3; ++nt) {
            acc[mt][nt] = (f32x4){0.f, 0.f, 0.f, 0.f};
            acc2[mt][nt] = (f32x4){0.f, 0.f, 0.f, 0.f};
        }

    for (int ks = 0; ks < KK; ks += 32) {
        __syncthreads();
        const _Float16* Ap[2] = {Ah, Al};
        const _Float16* Bp[2] = {WhT, WlT};
#pragma unroll
        for (int p = 0; p < 2; ++p) {
#pragma unroll
            for (int c = 0; c < (ROWS * 4 + 255) / 256; ++c) {
                int i = c * 256 + tid;  // 8-elem chunks; ROWS*32/8 total
                if (i < ROWS * 4) {
                    int r = i >> 2, kk = (i & 3) * 8;
                    f16x8 v = {};
                    if (row0 + r < M)
                        v = *reinterpret_cast<const f16x8*>(Ap[p] + (size_t)(row0 + r) * KK + ks + kk);
                    *reinterpret_cast<f16x8*>(&As[(p * ROWS + r) * STR + kk]) = v;
                }
            }
#pragma unroll
            for (int c = 0; c < (NN * 4 + 255) / 256; ++c) {
                int i = c * 256 + tid;
                if (i < NN * 4) {
                    int n = i >> 2, kk = (i & 3) * 8;
                    *reinterpret_cast<f16x8*>(&Bs[(p * NN + n) * STR + kk]) =
                        *reinterpret_cast<const f16x8*>(Bp[p] + (size_t)n * KK + ks + kk);
                }
            }
        }
        __syncthreads();
        const int kb = quad * 8;
        f16x8 ah[4], al[4], bh[3], bl[3];
#pragma unroll
        for (int mt = 0; mt < 4; ++mt) {
            ah[mt] = *reinterpret_cast<const f16x8*>(&As[(0 * ROWS + m0 + mt * 16 + l16) * STR + kb]);
            al[mt] = *reinterpret_cast<const f16x8*>(&As[(1 * ROWS + m0 + mt * 16 + l16) * STR + kb]);
        }
#pragma unroll
        for (int nt = 0; nt < 3; ++nt) {
            bh[nt] = *reinterpret_cast<const f16x8*>(&Bs[(0 * NN + n0w + nt * 16 + l16) * STR + kb]);
            bl[nt] = *reinterpret_cast<const f16x8*>(&Bs[(1 * NN + n0w + nt * 16 + l16) * STR + kb]);
        }
#pragma unroll
        for (int mt = 0; mt < 4; ++mt)
#pragma unroll
            for (int nt = 0; nt < 3; ++nt) {
                acc[mt][nt] = __builtin_amdgcn_mfma_f32_16x16x32_f16(ah[mt], bh[nt], acc[mt][nt], 0, 0, 0);
                acc2[mt][nt] = __builtin_amdgcn_mfma_f32_16x16x32_f16(ah[mt], bl[nt], acc2[mt][nt], 0, 0, 0);
                acc2[mt][nt] = __builtin_amdgcn_mfma_f32_16x16x32_f16(al[mt], bh[nt], acc2[mt][nt], 0, 0, 0);
            }
    }

    // epilogue: C/D layout col=lane&15, row=quad*4+reg (m89-verified)
    float bv[3];
#pragma unroll
    for (int nt = 0; nt < 3; ++nt) bv[nt] = bias ? bias[n0w + nt * 16 + l16] : 0.f;
#pragma unroll
    for (int mt = 0; mt < 4; ++mt)
#pragma unroll
        for (int i = 0; i < 4; ++i) {
            int row = row0 + m0 + mt * 16 + quad * 4 + i;
            if (row < M) {
                float rs = rowscale ? rowscale[row] : 1.f;
#pragma unroll
                for (int nt = 0; nt < 3; ++nt) {
                    int col = n0w + nt * 16 + l16;
                    float v = acc[mt][nt][i] + acc2[mt][nt][i] * (1.f / 2048.f) + bv[nt];
                    if (ACT == 1) v = fmaxf(v, 0.f);
                    v *= rs;
                    if (OM & 1) Cf[(size_t)row * NN + col] = v;
                    if (OM & 2) {
                        _Float16 hi = (_Float16)v;
                        Ch[(size_t)row * NN + col] = hi;
                        Cl[(size_t)row * NN + col] = (_Float16)((v - (float)hi) * 2048.f);
                    }
                }
            }
        }
}

// ---------------------------------------------------------------------------
// fp32 aggregation: one wave per node, lanes 0..47 x float4.
// h = h + relu(dinv[n]*(msc[n] + sum_e msc[src_e]) + B); h kept as fp16
// planes (hi + lo/2048), reconstructed/re-split in fp32 here.
// ---------------------------------------------------------------------------
__global__ __launch_bounds__(256) void aggregate_kernel(
    const float* __restrict__ msc, const int* __restrict__ csr,
    const int* __restrict__ rowptr, const float* __restrict__ dinv,
    const float* __restrict__ bias, _Float16* __restrict__ h_hi,
    _Float16* __restrict__ h_lo, int M) {
    int wid = (blockIdx.x * 256 + threadIdx.x) >> 6;
    int lane = threadIdx.x & 63;
    if (wid >= M || lane >= 48) return;
    const float4* base = reinterpret_cast<const float4*>(msc);
    float4 a = base[(size_t)wid * 48 + lane];  // self-loop (already * dinv[wid])
    float4 a2 = make_float4(0.f, 0.f, 0.f, 0.f);
    int beg = rowptr[wid], end = rowptr[wid + 1];
    int e = beg;
    for (; e + 1 < end; e += 2) {
        int s0 = csr[e], s1 = csr[e + 1];
        float4 v0 = base[(size_t)s0 * 48 + lane];
        float4 v1 = base[(size_t)s1 * 48 + lane];
        a.x += v0.x; a.y += v0.y; a.z += v0.z; a.w += v0.w;
        a2.x += v1.x; a2.y += v1.y; a2.z += v1.z; a2.w += v1.w;
    }
    if (e < end) {
        int s = csr[e];
        float4 v = base[(size_t)s * 48 + lane];
        a.x += v.x; a.y += v.y; a.z += v.z; a.w += v.w;
    }
    a.x += a2.x; a.y += a2.y; a.z += a2.z; a.w += a2.w;
    float dn = dinv[wid];
    float4 b = reinterpret_cast<const float4*>(bias)[lane];
    f16x4* hip = reinterpret_cast<f16x4*>(h_hi) + (size_t)wid * 48 + lane;
    f16x4* lop = reinterpret_cast<f16x4*>(h_lo) + (size_t)wid * 48 + lane;
    f16x4 hh = *hip, hl = *lop;
    float4 hv;
    hv.x = (float)hh[0] + (float)hl[0] * (1.f / 2048.f) + fmaxf(a.x * dn + b.x, 0.f);
    hv.y = (float)hh[1] + (float)hl[1] * (1.f / 2048.f) + fmaxf(a.y * dn + b.y, 0.f);
    hv.z = (float)hh[2] + (float)hl[2] * (1.f / 2048.f) + fmaxf(a.z * dn + b.z, 0.f);
    hv.w = (float)hh[3] + (float)hl[3] * (1.f / 2048.f) + fmaxf(a.w * dn + b.w, 0.f);
    f16x4 nh = {(_Float16)hv.x, (_Float16)hv.y, (_Float16)hv.z, (_Float16)hv.w};
    f16x4 nl = {(_Float16)((hv.x - (float)nh[0]) * 2048.f),
                (_Float16)((hv.y - (float)nh[1]) * 2048.f),
                (_Float16)((hv.z - (float)nh[2]) * 2048.f),
                (_Float16)((hv.w - (float)nh[3]) * 2048.f)};
    *hip = nh;
    *lop = nl;
}

// ---------------------------------------------------------------------------
// Tail (fp32, as round-1 which passed): pos = p2@Wp3+bp3; rad = sigmoid(r@Wr2+br2);
// out = pos/(|pos|+1e-8)*rad
// ---------------------------------------------------------------------------
__global__ void finalize_kernel(const float* __restrict__ p2, const float* __restrict__ rbuf,
                                const float* __restrict__ Wp3, const float* __restrict__ bp3,
                                const float* __restrict__ Wr2, const float* __restrict__ br2,
                                float* __restrict__ out, int M) {
    int n = blockIdx.x * 256 + threadIdx.x;
    if (n >= M) return;
    const float4* p = reinterpret_cast<const float4*>(p2 + (size_t)n * 96);
    const float4* r = reinterpret_cast<const float4*>(rbuf + (size_t)n * 96);
    float a0 = 0.f, a1 = 0.f, rr = 0.f;
#pragma unroll
    for (int q = 0; q < 24; q++) {
        float4 pv = p[q];
        float4 rv = r[q];
        float4 w01 = reinterpret_cast<const float4*>(Wp3)[2 * q];
        float4 w23 = reinterpret_cast<const float4*>(Wp3)[2 * q + 1];
        a0 += pv.x * w01.x + pv.y * w01.z + pv.z * w23.x + pv.w * w23.z;
        a1 += pv.x * w01.y + pv.y * w01.w + pv.z * w23.y + pv.w * w23.w;
        float4 wr = reinterpret_cast<const float4*>(Wr2)[q];
        rr += rv.x * wr.x + rv.y * wr.y + rv.z * wr.z + rv.w * wr.w;
    }
    a0 += bp3[0];
    a1 += bp3[1];
    rr += br2[0];
    float radius = 1.f / (1.f + expf(-rr));
    float nrm = sqrtf(a0 * a0 + a1 * a1) + 1e-8f;
    float s = radius / nrm;
    out[(size_t)n * 2 + 0] = a0 * s;
    out[(size_t)n * 2 + 1] = a1 * s;
}

extern "C" void kernel_launch(void* const* d_in, const int* in_sizes, int n_in,
                              void* d_out, int out_size, void* d_ws, size_t ws_size,
                              hipStream_t stream) {
    const float* x     = (const float*)d_in[0];
    const int*   ei    = (const int*)d_in[1];
    const float* Wp    = (const float*)d_in[2];
    const float* bp    = (const float*)d_in[3];
    const float* convW = (const float*)d_in[4];
    const float* convB = (const float*)d_in[5];
    const float* Wp1   = (const float*)d_in[6];
    const float* bp1   = (const float*)d_in[7];
    const float* Wp2   = (const float*)d_in[8];
    const float* bp2   = (const float*)d_in[9];
    const float* Wp3   = (const float*)d_in[10];
    const float* bp3   = (const float*)d_in[11];
    const float* Wr1   = (const float*)d_in[12];
    const float* br1   = (const float*)d_in[13];
    const float* Wr2   = (const float*)d_in[14];
    const float* br2   = (const float*)d_in[15];
    float* out = (float*)d_out;

    const int M = in_sizes[0] / 128;  // 50000
    const int E = in_sizes[1] / 2;    // 800000
    const int* srcI = ei;
    const int* dstI = ei + E;

    char* w = (char*)d_ws;
    size_t off = 0;
    auto alloc = [&](size_t b) { size_t o = off; off += (b + 255) & ~(size_t)255; return o; };
    float*    msc  = (float*)(w + alloc((size_t)M * 192 * 4));
    _Float16* h_hi = (_Float16*)(w + alloc((size_t)M * 192 * 2));
    _Float16* h_lo = (_Float16*)(w + alloc((size_t)M * 192 * 2));
    char*     xreg = w + alloc((size_t)M * 128 * 2 * 2);  // xh+xl; later p2 (19.2<=25.6MB)
    float*    rb   = (float*)(w + alloc((size_t)M * 96 * 4));
    _Float16* WphT  = (_Float16*)(w + alloc((size_t)128 * 192 * 2));
    _Float16* WplT  = (_Float16*)(w + alloc((size_t)128 * 192 * 2));
    _Float16* cWhT  = (_Float16*)(w + alloc((size_t)4 * 192 * 192 * 2));
    _Float16* cWlT  = (_Float16*)(w + alloc((size_t)4 * 192 * 192 * 2));
    _Float16* Wp1hT = (_Float16*)(w + alloc((size_t)192 * 192 * 2));
    _Float16* Wp1lT = (_Float16*)(w + alloc((size_t)192 * 192 * 2));
    _Float16* Wp2hT = (_Float16*)(w + alloc((size_t)96 * 192 * 2));
    _Float16* Wp2lT = (_Float16*)(w + alloc((size_t)96 * 192 * 2));
    _Float16* Wr1hT = (_Float16*)(w + alloc((size_t)96 * 192 * 2));
    _Float16* Wr1lT = (_Float16*)(w + alloc((size_t)96 * 192 * 2));
    int*      cnt    = (int*)(w + alloc((size_t)M * 4));
    float*    dinv   = (float*)(w + alloc((size_t)M * 4));
    int*      rowptr = (int*)(w + alloc((size_t)(M + 1) * 4));
    int*      cursor = (int*)(w + alloc((size_t)M * 4));
    int*      csr    = (int*)(w + alloc((size_t)E * 4));
    int*      bsum   = (int*)(w + alloc(256 * 4));
    int*      boff   = (int*)(w + alloc(256 * 4));

    _Float16* xh  = (_Float16*)xreg;
    _Float16* xl  = xh + (size_t)M * 128;
    float*    p2  = (float*)xreg;          // alias: x planes dead after proj
    _Float16* p1h = (_Float16*)msc;        // alias: msc dead after last aggregate
    _Float16* p1l = p1h + (size_t)M * 192; // 2*19.2MB == msc's 38.4MB

    hipMemsetAsync(cnt, 0, (size_t)M * 4, stream);
    hipMemsetAsync(cursor, 0, (size_t)M * 4, stream);

    // graph setup
    count_kernel<<<(E + 255) / 256, 256, 0, stream>>>(dstI, E, cnt);
    dinv_kernel<<<(M + 255) / 256, 256, 0, stream>>>(cnt, M, dinv);
    int nb = (M + 255) / 256;
    scan1_kernel<<<nb, 256, 0, stream>>>(cnt, M, rowptr, bsum);
    scan2_kernel<<<1, 256, 0, stream>>>(bsum, nb, boff);
    scan3_kernel<<<(M + 256) / 256, 256, 0, stream>>>(rowptr, M, E, boff);
    fill_kernel<<<(E + 255) / 256, 256, 0, stream>>>(srcI, dstI, E, rowptr, cursor, csr);

    // conversions
    convert_x_kernel<<<((M * 128 / 4) + 255) / 256, 256, 0, stream>>>(x, xh, xl, M * 128 / 4);
    WSegs segs;
    segs.s[0] = {Wp, WphT, WplT, 128, 192};
    segs.s[1] = {convW + 0 * 192 * 192, cWhT + 0 * 192 * 192, cWlT + 0 * 192 * 192, 192, 192};
    segs.s[2] = {convW + 1 * 192 * 192, cWhT + 1 * 192 * 192, cWlT + 1 * 192 * 192, 192, 192};
    segs.s[3] = {convW + 2 * 192 * 192, cWhT + 2 * 192 * 192, cWlT + 2 * 192 * 192, 192, 192};
    segs.s[4] = {convW + 3 * 192 * 192, cWhT + 3 * 192 * 192, cWlT + 3 * 192 * 192, 192, 192};
    segs.s[5] = {Wp1, Wp1hT, Wp1lT, 192, 192};
    segs.s[6] = {Wp2, Wp2hT, Wp2lT, 192, 96};
    segs.s[7] = {Wr1, Wr1hT, Wr1lT, 192, 96};
    convert_wt_kernel<<<dim3(144, 8), 256, 0, stream>>>(segs);

    const int gb192 = (M + 63) / 64;    // 782
    const int gb96  = (M + 127) / 128;  // 391

    // h = x @ Wp + bp -> planes
    mfma_gemm<128, 192, 0, 2><<<gb192, 256, 0, stream>>>(
        xh, xl, WphT, WplT, bp, nullptr, nullptr, h_hi, h_lo, M);
    // 4 GCN layers: msc = (h@W)*dinv (fp32), then gather-aggregate
    for (int i = 0; i < 4; i++) {
        mfma_gemm<192, 192, 0, 1><<<gb192, 256, 0, stream>>>(
            h_hi, h_lo, cWhT + (size_t)i * 192 * 192, cWlT + (size_t)i * 192 * 192,
            nullptr, dinv, msc, nullptr, nullptr, M);
        aggregate_kernel<<<(M + 3) / 4, 256, 0, stream>>>(
            msc, csr, rowptr, dinv, convB + (size_t)i * 192, h_hi, h_lo, M);
    }
    // heads
    mfma_gemm<192, 192, 1, 2><<<gb192, 256, 0, stream>>>(
        h_hi, h_lo, Wp1hT, Wp1lT, bp1, nullptr, nullptr, p1h, p1l, M);
    mfma_gemm<192, 96, 1, 1><<<gb96, 256, 0, stream>>>(
        p1h, p1l, Wp2hT, Wp2lT, bp2, nullptr, p2, nullptr, nullptr, M);
    mfma_gemm<192, 96, 1, 1><<<gb96, 256, 0, stream>>>(
        h_hi, h_lo, Wr1hT, Wr1lT, br1, nullptr, rb, nullptr, nullptr, M);
    finalize_kernel<<<(M + 255) / 256, 256, 0, stream>>>(p2, rb, Wp3, bp3, Wr2, br2, out, M);
}